// Round 5
// baseline (749.727 us; speedup 1.0000x reference)
//
#include <hip/hip_runtime.h>
#include <hip/hip_fp16.h>
#include <cstdint>
#include <cstddef>

#define EPSV 1e-5f

typedef _Float16 f16x8 __attribute__((ext_vector_type(8)));
typedef float f32x4 __attribute__((ext_vector_type(4)));
typedef short short4v __attribute__((ext_vector_type(4)));

__device__ __forceinline__ short f2h(float f) {
    _Float16 h = (_Float16)f;
    union { _Float16 h; short s; } u; u.h = h; return u.s;
}
__device__ __forceinline__ __half2 u2h2(unsigned u) {
    union { unsigned u; __half2 h; } x; x.u = u; return x.h;
}
__device__ __forceinline__ unsigned packh2(float w) {
    _Float16 h = (_Float16)w;
    union { _Float16 h; unsigned short s; } u; u.h = h;
    return (unsigned)u.s * 0x10001u;
}

// ================= fused prep kernel =================
// ranges: [0,1024) zero | [1024,1536) w1 | [1536,1856) wfuse | [1856,1928) dtab0
//         [1928,2440) convoff | [2440,5512) convw9 | [5512,6536) xpose | [6536,10632) gap
__global__ __launch_bounds__(256) void k_prep(
    const float* __restrict__ x, short* __restrict__ xT,
    const float* __restrict__ w1, short* __restrict__ A1,
    const float* __restrict__ wfuse, short* __restrict__ Af,
    int* __restrict__ dtab0,
    const float* __restrict__ woff1, const float* __restrict__ wm1,
    const float* __restrict__ woff2, const float* __restrict__ wm2,
    const float* __restrict__ woff3, const float* __restrict__ wm3,
    const float* __restrict__ woff4, const float* __restrict__ wm4,
    short* __restrict__ Aoff,
    const float* __restrict__ w2, const float* __restrict__ w3, const float* __restrict__ w4,
    short* __restrict__ A2, short* __restrict__ A3, short* __restrict__ A4,
    float4* __restrict__ zbase, float* __restrict__ gap)
{
    __shared__ short lds9[4608];
    __shared__ float lsg[4];
    int bx = blockIdx.x, t = threadIdx.x;
    if (bx < 1024) {
        for (int i = bx * 256 + t; i < 720896; i += 262144)
            zbase[i] = float4{0.f, 0.f, 0.f, 0.f};
        return;
    }
    if (bx < 1536) {
        int i4 = (bx - 1024) * 256 + t;
        float4 v = ((const float4*)w1)[i4];
        ((short4v*)A1)[i4] = short4v{f2h(v.x), f2h(v.y), f2h(v.z), f2h(v.w)};
        return;
    }
    if (bx < 1856) {
        int i4 = (bx - 1536) * 256 + t;
        float4 v = ((const float4*)wfuse)[i4];
        ((short4v*)Af)[i4] = short4v{f2h(v.x), f2h(v.y), f2h(v.z), f2h(v.w)};
        return;
    }
    if (bx < 1928) {
        int i = (bx - 1856) * 256 + t;
        if (i >= 9 * 2048) return;
        int j = i >> 11, p = i & 2047;
        int hw = p & 1023, h = hw >> 5, w = hw & 31;
        int y = h + j / 3 - 1, xx = w + j % 3 - 1;
        bool v = (y >= 0 && y < 32 && xx >= 0 && xx < 32);
        int4 ii = {v ? y * 32 + xx : 0, 0, 0, 0};
        uint4 ww = {v ? packh2(1.f) : 0u, 0u, 0u, 0u};
        ((int4*)dtab0)[(size_t)i * 2] = ii;
        ((uint4*)dtab0)[(size_t)i * 2 + 1] = ww;
        return;
    }
    if (bx < 2440) {
        int qb = bx - 1928;
        int ch = qb >> 2, cch = qb & 3;
        short* dbase = Aoff + (size_t)ch * 18432 + cch * 512;
        if (ch >= 84) {
            #pragma unroll
            for (int s = 0; s < 18; s++) {
                int idx = s * 256 + t;
                int jj = idx >> 9, c = idx & 511;
                dbase[(size_t)jj * 2048 + c] = 0;
            }
            return;
        }
        const float* src; int oc;
        if (ch < 2)       { src = woff1; oc = ch; }
        else if (ch == 2) { src = wm1;   oc = 0; }
        else if (ch < 21) { src = woff2; oc = ch - 3; }
        else if (ch < 30) { src = wm2;   oc = ch - 21; }
        else if (ch < 48) { src = woff3; oc = ch - 30; }
        else if (ch < 57) { src = wm3;   oc = ch - 48; }
        else if (ch < 75) { src = woff4; oc = ch - 57; }
        else              { src = wm4;   oc = ch - 75; }
        const float* basep = src + ((size_t)oc * 2048 + cch * 512) * 9;
        #pragma unroll
        for (int s = 0; s < 18; s++) {
            int idx = s * 256 + t;
            int c = idx / 9, jj = idx - c * 9;
            lds9[jj * 512 + c] = f2h(basep[idx]);
        }
        __syncthreads();
        #pragma unroll
        for (int s = 0; s < 18; s++) {
            int idx = s * 256 + t;
            int jj = idx >> 9, c = idx & 511;
            dbase[(size_t)jj * 2048 + c] = lds9[idx];
        }
        return;
    }
    if (bx < 5512) {
        int qb = bx - 2440;
        int o = qb & 255, cch = (qb >> 8) & 3, br = qb >> 10;
        const float* src = br == 0 ? w2 : br == 1 ? w3 : w4;
        short* dst = br == 0 ? A2 : br == 1 ? A3 : A4;
        const float* basep = src + ((size_t)o * 2048 + cch * 512) * 9;
        #pragma unroll
        for (int s = 0; s < 18; s++) {
            int idx = s * 256 + t;
            int c = idx / 9, jj = idx - c * 9;
            lds9[jj * 512 + c] = f2h(basep[idx]);
        }
        __syncthreads();
        short* dbase = dst + (size_t)o * 18432 + cch * 512;
        #pragma unroll
        for (int s = 0; s < 18; s++) {
            int idx = s * 256 + t;
            int jj = idx >> 9, c = idx & 511;
            dbase[(size_t)jj * 2048 + c] = lds9[idx];
        }
        return;
    }
    if (bx < 6536) {
        int qb = bx - 5512;
        int hw0 = (qb & 15) * 64, c0 = ((qb >> 4) & 31) * 64, b = qb >> 9;
        const float* xb = x + (size_t)b * 2048 * 1024;
        int hwi = t & 63, cr = t >> 6;
        #pragma unroll
        for (int r = 0; r < 16; r++) {
            int cl = cr + r * 4;
            lds9[hwi * 72 + cl] = f2h(xb[(size_t)(c0 + cl) * 1024 + hw0 + hwi]);
        }
        __syncthreads();
        short* xTb = xT + (size_t)b * 1024 * 2048;
        int ci = t & 63, hr = t >> 6;
        #pragma unroll
        for (int r = 0; r < 16; r++) {
            int hwr = hr + r * 4;
            xTb[(size_t)(hw0 + hwr) * 2048 + c0 + ci] = lds9[hwr * 72 + ci];
        }
        return;
    }
    {
        int bc = bx - 6536;                 // [0,4096) = [b][c]
        const float* row = x + (size_t)bc * 1024;
        float s = row[t] + row[t + 256] + row[t + 512] + row[t + 768];
        #pragma unroll
        for (int off = 32; off; off >>= 1) s += __shfl_down(s, off);
        if ((t & 63) == 0) lsg[t >> 6] = s;
        __syncthreads();
        if (t == 0) gap[bc] = (lsg[0] + lsg[1] + lsg[2] + lsg[3]) * (1.f / 1024.f);
    }
}

// ---------------- deform sampling tables (ii + packed-f16 tap weights) ----------------
__global__ void k_sample(const float* OM, int* dtabi) {
    int i = blockIdx.x * 256 + threadIdx.x;
    if (i >= 57344) return;
    int br, j, p;
    if (i < 2048) { br = 0; j = 0; p = i; }
    else { int r = i - 2048; br = 1 + r / 18432; r %= 18432; j = r >> 11; p = r & 2047; }
    const int dil_[4] = {1, 6, 12, 18};
    const int pad_[4] = {0, 6, 12, 18};
    const int cho_[4] = {0, 3, 30, 57};
    const int chm_[4] = {2, 21, 48, 75};
    const int tbo_[4] = {0, 2048, 20480, 38912};
    int J = br ? 9 : 1;
    int dil = dil_[br], pad = pad_[br];
    int hw = p & 1023, h = hw >> 5, w = hw & 31;
    float offy = OM[(size_t)(cho_[br] + j) * 2048 + p];
    float offx = OM[(size_t)(cho_[br] + J + j) * 2048 + p];
    float mz   = OM[(size_t)(chm_[br] + j) * 2048 + p];
    float m = 1.f / (1.f + expf(-mz));
    int ky = j / 3, kx = j - ky * 3;
    float fh = (float)(h + ky * dil) + offy;
    float fw = (float)(w + kx * dil) + offx;
    int limi = 31 + 2 * pad;
    float lim = (float)limi;
    fh = fminf(fmaxf(fh, 0.f), lim);
    fw = fminf(fmaxf(fw, 0.f), lim);
    float y0f = floorf(fh), x0f = floorf(fw);
    float wy = fh - y0f, wx = fw - x0f;
    int y0 = (int)y0f, x0 = (int)x0f;
    int y1 = min(y0 + 1, limi), x1 = min(x0 + 1, limi);
    int4 ii; uint4 ww;
    {
        int yo = y0 - pad, xo = x0 - pad;
        bool v = ((unsigned)yo < 32u) && ((unsigned)xo < 32u);
        ii.x = v ? yo * 32 + xo : 0; ww.x = v ? packh2((1.f - wy) * (1.f - wx) * m) : 0u;
    }
    {
        int yo = y0 - pad, xo = x1 - pad;
        bool v = ((unsigned)yo < 32u) && ((unsigned)xo < 32u);
        ii.y = v ? yo * 32 + xo : 0; ww.y = v ? packh2((1.f - wy) * wx * m) : 0u;
    }
    {
        int yo = y1 - pad, xo = x0 - pad;
        bool v = ((unsigned)yo < 32u) && ((unsigned)xo < 32u);
        ii.z = v ? yo * 32 + xo : 0; ww.z = v ? packh2(wy * (1.f - wx) * m) : 0u;
    }
    {
        int yo = y1 - pad, xo = x1 - pad;
        bool v = ((unsigned)yo < 32u) && ((unsigned)xo < 32u);
        ii.w = v ? yo * 32 + xo : 0; ww.w = v ? packh2(wy * wx * m) : 0u;
    }
    int ent = tbo_[br] + j * 2048 + p;
    ((int4*)dtabi)[(size_t)ent * 2] = ii;
    ((uint4*)dtabi)[(size_t)ent * 2 + 1] = ww;
}

// ================= gather GEMM, 2-deep pipelined =================
// (WM*64)x128 tile, BK=32, 16x16x32 f16. Loads issued at iter i consumed at i+2.
template <int WM, int NTAP>
__device__ __forceinline__ void gemm_gather_f16(
    const short* __restrict__ A, const int* __restrict__ tab,
    const short* __restrict__ xT, float* __restrict__ C,
    int K, int kbeg, int kend, int nbase)
{
    constexpr int TPP = WM;          // threads per position
    constexpr int CPT = 32 / TPP;    // channels per thread
    constexpr int NG = CPT / 8;      // uint4 groups per tap
    __shared__ __align__(16) short At[WM * 64][40];
    __shared__ __align__(16) short Bt[128][40];
    int t = threadIdx.x;
    f32x4 acc[4][4] = {};

    int p = t / TPP;
    int q = (t % TPP) * CPT;
    int pg = nbase + p;
    int bb = nbase >> 10;
    int jj = kbeg >> 11;
    const int4* te = (const int4*)tab + ((size_t)jj * 2048 + pg) * 2;
    int4 ii = te[0];
    uint4 wp = *(const uint4*)(te + 1);
    __half2 wt0 = u2h2(wp.x), wt1 = u2h2(wp.y), wt2 = u2h2(wp.z), wt3 = u2h2(wp.w);
    const short* xbase = xT + (size_t)bb * 1024 * 2048 + q;
    const short* rp0 = xbase + (size_t)ii.x * 2048;
    const short* rp1 = xbase + (size_t)ii.y * 2048;
    const short* rp2 = xbase + (size_t)ii.z * 2048;
    const short* rp3 = xbase + (size_t)ii.w * 2048;

    int arow = t >> 1;
    int aseg = (t & 1) * 16;
    const short* Ar = A + (size_t)arow * K + aseg;

    int lane = t & 63, wv = t >> 6;
    int mq = (wv >> 1) * 64, nq = (wv & 1) * 64;
    int lm = lane & 15, quad = lane >> 4;

    uint4 Aa[2], Ab[2];
    uint4 G0[2][NG], G1[2][NG], G2[2][NG], G3[2][NG];

#define LDSTAGE(S, KK) { \
    int ck_ = (KK) & 2047; \
    Aa[S] = *(const uint4*)(Ar + (KK)); \
    Ab[S] = *(const uint4*)(Ar + (KK) + 8); \
    _Pragma("unroll") \
    for (int g = 0; g < NG; g++) { \
        int o8_ = ck_ + g * 8; \
        G0[S][g] = *(const uint4*)(rp0 + o8_); \
        if (NTAP == 4) { \
            G1[S][g] = *(const uint4*)(rp1 + o8_); \
            G2[S][g] = *(const uint4*)(rp2 + o8_); \
            G3[S][g] = *(const uint4*)(rp3 + o8_); \
        } \
    } }

#define STEP(S, KPRE) { \
    uint4 pk[NG]; \
    _Pragma("unroll") \
    for (int g = 0; g < NG; g++) { \
        __half2 r0 = __hmul2(u2h2(G0[S][g].x), wt0); \
        __half2 r1 = __hmul2(u2h2(G0[S][g].y), wt0); \
        __half2 r2 = __hmul2(u2h2(G0[S][g].z), wt0); \
        __half2 r3 = __hmul2(u2h2(G0[S][g].w), wt0); \
        if (NTAP == 4) { \
            r0 = __hfma2(u2h2(G1[S][g].x), wt1, r0); \
            r1 = __hfma2(u2h2(G1[S][g].y), wt1, r1); \
            r2 = __hfma2(u2h2(G1[S][g].z), wt1, r2); \
            r3 = __hfma2(u2h2(G1[S][g].w), wt1, r3); \
            r0 = __hfma2(u2h2(G2[S][g].x), wt2, r0); \
            r1 = __hfma2(u2h2(G2[S][g].y), wt2, r1); \
            r2 = __hfma2(u2h2(G2[S][g].z), wt2, r2); \
            r3 = __hfma2(u2h2(G2[S][g].w), wt2, r3); \
            r0 = __hfma2(u2h2(G3[S][g].x), wt3, r0); \
            r1 = __hfma2(u2h2(G3[S][g].y), wt3, r1); \
            r2 = __hfma2(u2h2(G3[S][g].z), wt3, r2); \
            r3 = __hfma2(u2h2(G3[S][g].w), wt3, r3); \
        } \
        union { __half2 h[4]; uint4 u; } uu; \
        uu.h[0] = r0; uu.h[1] = r1; uu.h[2] = r2; uu.h[3] = r3; \
        pk[g] = uu.u; \
    } \
    __syncthreads(); \
    *(uint4*)&At[arow][aseg]     = Aa[S]; \
    *(uint4*)&At[arow][aseg + 8] = Ab[S]; \
    _Pragma("unroll") \
    for (int g = 0; g < NG; g++) *(uint4*)&Bt[p][q + g * 8] = pk[g]; \
    LDSTAGE(S, KPRE); \
    __syncthreads(); \
    f16x8 af[4], bfv[4]; \
    _Pragma("unroll") \
    for (int f = 0; f < 4; f++) { \
        af[f]  = *(const f16x8*)&At[mq + f * 16 + lm][quad * 8]; \
        bfv[f] = *(const f16x8*)&Bt[nq + f * 16 + lm][quad * 8]; \
    } \
    _Pragma("unroll") \
    for (int fm = 0; fm < 4; fm++) \
        _Pragma("unroll") \
        for (int fn = 0; fn < 4; fn++) \
            acc[fm][fn] = __builtin_amdgcn_mfma_f32_16x16x32_f16(af[fm], bfv[fn], acc[fm][fn], 0, 0, 0); \
}

    LDSTAGE(0, kbeg);
    LDSTAGE(1, kbeg + 32);
    for (int k0 = kbeg; k0 < kend; k0 += 64) {
        int kp0 = k0 + 64; if (kp0 >= kend) kp0 = kbeg;
        int kp1 = k0 + 96; if (kp1 >= kend) kp1 = kbeg;
        STEP(0, kp0);
        STEP(1, kp1);
    }
#undef LDSTAGE
#undef STEP

    #pragma unroll
    for (int fm = 0; fm < 4; fm++) {
        int row0 = mq + fm * 16 + quad * 4;
        #pragma unroll
        for (int fn = 0; fn < 4; fn++) {
            int col = nbase + nq + fn * 16 + lm;
            #pragma unroll
            for (int r = 0; r < 4; r++)
                atomicAdd(&C[(size_t)(row0 + r) * 2048 + col], acc[fm][fn][r]);
        }
    }
}

// offset/mod conv GEMM: M=128, K=18432, kchunk=512, grid (16,1,36), block 256, 1 tap
__global__ __launch_bounds__(256, 4) void k_ogemm(const short* __restrict__ Aoff,
                                                  const int* __restrict__ dtab0,
                                                  const short* __restrict__ xT,
                                                  float* __restrict__ offmod) {
    int kbeg = blockIdx.z * 512;
    gemm_gather_f16<2, 1>(Aoff, dtab0, xT, offmod, 18432, kbeg, kbeg + 512, blockIdx.x * 128);
}

// merged 4-branch deform GEMM: M=256, kchunk=1024, grid (16,1,56), block 512, 4 taps
__global__ __launch_bounds__(512, 4) void k_dgemm(const short* __restrict__ Aall,
                                                  const int* __restrict__ dtab,
                                                  const short* __restrict__ xT,
                                                  float* __restrict__ ypre) {
    int z = blockIdx.z;
    int br, kbeg;
    if (z < 2) { br = 0; kbeg = z * 1024; }
    else { int zz = z - 2; br = 1 + zz / 18; kbeg = (zz % 18) * 1024; }
    const size_t aoffs[4] = {0, 524288, 524288 + 4718592, 524288 + 2 * (size_t)4718592};
    const int tbo[4] = {0, 2048, 20480, 38912};
    int K = br ? 18432 : 2048;
    gemm_gather_f16<4, 4>(Aall + aoffs[br], dtab + (size_t)tbo[br] * 8, xT,
                          ypre + (size_t)br * 524288, K, kbeg, kbeg + 1024, blockIdx.x * 128);
}

// fuse GEMM: dense B [2048][1280] f16, M=256, K=1280, kchunk=160, grid (16,2,8)
__global__ __launch_bounds__(256) void k_fgemm(const short* __restrict__ A,
                                               const short* __restrict__ Bp,
                                               float* __restrict__ C) {
    __shared__ __align__(16) short At[128][40];
    __shared__ __align__(16) short Bt[128][40];
    int t = threadIdx.x;
    int nbase = blockIdx.x * 128, mbase = blockIdx.y * 128;
    int kbeg = blockIdx.z * 160, kend = kbeg + 160;
    const int K = 1280;
    f32x4 acc[4][4] = {};
    int lane = t & 63, wv = t >> 6;
    int mq = (wv >> 1) * 64, nq = (wv & 1) * 64;
    int lm = lane & 15, quad = lane >> 4;
    for (int k0 = kbeg; k0 < kend; k0 += 32) {
        int row = t >> 2, seg = t & 3;
        *(uint4*)&At[row][seg * 8] = *(const uint4*)(A + (size_t)(mbase + row) * K + k0 + seg * 8);
        *(uint4*)&At[row + 64][seg * 8] = *(const uint4*)(A + (size_t)(mbase + row + 64) * K + k0 + seg * 8);
        *(uint4*)&Bt[row][seg * 8] = *(const uint4*)(Bp + (size_t)(nbase + row) * K + k0 + seg * 8);
        *(uint4*)&Bt[row + 64][seg * 8] = *(const uint4*)(Bp + (size_t)(nbase + row + 64) * K + k0 + seg * 8);
        __syncthreads();
        f16x8 af[4], bfv[4];
        #pragma unroll
        for (int f = 0; f < 4; f++) {
            af[f]  = *(const f16x8*)&At[mq + f * 16 + lm][quad * 8];
            bfv[f] = *(const f16x8*)&Bt[nq + f * 16 + lm][quad * 8];
        }
        #pragma unroll
        for (int fm = 0; fm < 4; fm++)
            #pragma unroll
            for (int fn = 0; fn < 4; fn++)
                acc[fm][fn] = __builtin_amdgcn_mfma_f32_16x16x32_f16(af[fm], bfv[fn], acc[fm][fn], 0, 0, 0);
        __syncthreads();
    }
    #pragma unroll
    for (int fm = 0; fm < 4; fm++) {
        int row0 = mbase + mq + fm * 16 + quad * 4;
        #pragma unroll
        for (int fn = 0; fn < 4; fn++) {
            int col = nbase + nq + fn * 16 + lm;
            #pragma unroll
            for (int r = 0; r < 4; r++)
                atomicAdd(&C[(size_t)(row0 + r) * 2048 + col], acc[fm][fn][r]);
        }
    }
}

// ---------------- BN stats (y<4) + pool branch (y==4) ----------------
__global__ void k_bnpool(const float* Y0, const float* Y1, const float* Y2, const float* Y3,
                         const float* g0, const float* g1, const float* g2, const float* g3,
                         const float* b0, const float* b1, const float* b2, const float* b3,
                         float* S,
                         const float* gap, const float* wpool, const float* gp,
                         const float* bp, float* pfin) {
    int br = blockIdx.y;
    int o = blockIdx.x, t = threadIdx.x;
    __shared__ float l0[4], l1[4];
    if (br == 4) {
        float s0 = 0.f, s1 = 0.f;
        const float* wr = wpool + (size_t)o * 2048;
        for (int c = t; c < 2048; c += 256) {
            float wv = wr[c];
            s0 += wv * gap[c];
            s1 += wv * gap[2048 + c];
        }
        #pragma unroll
        for (int off = 32; off; off >>= 1) { s0 += __shfl_down(s0, off); s1 += __shfl_down(s1, off); }
        int wv_ = t >> 6;
        if ((t & 63) == 0) { l0[wv_] = s0; l1[wv_] = s1; }
        __syncthreads();
        if (t == 0) {
            float p0 = l0[0] + l0[1] + l0[2] + l0[3];
            float p1 = l1[0] + l1[1] + l1[2] + l1[3];
            float mu = 0.5f * (p0 + p1);
            float d0 = p0 - mu, d1 = p1 - mu;
            float var = 0.5f * (d0 * d0 + d1 * d1);
            float r = rsqrtf(var + EPSV);
            pfin[o]       = fmaxf(d0 * r * gp[o] + bp[o], 0.f);
            pfin[256 + o] = fmaxf(d1 * r * gp[o] + bp[o], 0.f);
        }
        return;
    }
    const float* Y = br == 0 ? Y0 : br == 1 ? Y1 : br == 2 ? Y2 : Y3;
    const float* g = br == 0 ? g0 : br == 1 ? g1 : br == 2 ? g2 : g3;
    const float* b = br == 0 ? b0 : br == 1 ? b1 : br == 2 ? b2 : b3;
    float* so = S + (size_t)br * 512;
    const float* row = Y + (size_t)o * 2048;
    float s = 0.f, ss = 0.f;
    for (int i = t; i < 2048; i += 256) { float v = row[i]; s += v; ss += v * v; }
    #pragma unroll
    for (int off = 32; off; off >>= 1) { s += __shfl_down(s, off); ss += __shfl_down(ss, off); }
    int wv = t >> 6;
    if ((t & 63) == 0) { l0[wv] = s; l1[wv] = ss; }
    __syncthreads();
    if (t == 0) {
        s = l0[0] + l0[1] + l0[2] + l0[3];
        ss = l1[0] + l1[1] + l1[2] + l1[3];
        float mu = s * (1.f / 2048.f);
        float var = ss * (1.f / 2048.f) - mu * mu;
        float sc = g[o] * rsqrtf(var + EPSV);
        so[o] = sc;
        so[256 + o] = b[o] - mu * sc;
    }
}

// ---------------- xcat transpose: ypre[1024ch][2048p] (BN+relu) + pfin -> xcat[p][1280] f16 ----------------
__global__ void k_xcat(const float* __restrict__ ypre, const float* __restrict__ S,
                       const float* __restrict__ pfin, short* __restrict__ xcat) {
    int p0 = blockIdx.x * 64, ct = blockIdx.y;
    int t = threadIdx.x;
    if (ct >= 16) {
        int c0 = 1024 + (ct - 16) * 64;
        int ci = t & 63, pr = t >> 6;
        #pragma unroll
        for (int r = 0; r < 16; r++) {
            int pw = p0 + pr + r * 4;
            int b = pw >> 10;
            xcat[(size_t)pw * 1280 + c0 + ci] = f2h(pfin[b * 256 + (c0 - 1024) + ci]);
        }
        return;
    }
    __shared__ short tile[64][72];
    int c0 = ct * 64;
    int pi = t & 63, cr = t >> 6;
    #pragma unroll
    for (int r = 0; r < 16; r++) {
        int cl = cr + r * 4;
        int cg = c0 + cl;
        int br = cg >> 8, cc = cg & 255;
        float sc = S[br * 512 + cc], sh = S[br * 512 + 256 + cc];
        float v = fmaxf(ypre[(size_t)cg * 2048 + p0 + pi] * sc + sh, 0.f);
        tile[pi][cl] = f2h(v);
    }
    __syncthreads();
    int ci = t & 63, pr = t >> 6;
    #pragma unroll
    for (int r = 0; r < 16; r++) {
        int pw = pr + r * 4;
        xcat[(size_t)(p0 + pw) * 1280 + c0 + ci] = tile[pw][ci];
    }
}

// ---------------- final BN + relu + layout to [B][O][HW] ----------------
__global__ void k_final(const float* outpre, const float* S, float* dout) {
    int i = blockIdx.x * 256 + threadIdx.x;    // 524288
    int hw = i & 1023, o = (i >> 10) & 255, b = i >> 18;
    float v = outpre[(size_t)o * 2048 + b * 1024 + hw] * S[o] + S[256 + o];
    dout[i] = fmaxf(v, 0.f);
}

extern "C" void kernel_launch(void* const* d_in, const int* in_sizes, int n_in,
                              void* d_out, int out_size, void* d_ws, size_t ws_size,
                              hipStream_t stream) {
    const float* x     = (const float*)d_in[0];
    const float* woff1 = (const float*)d_in[1];
    const float* wm1   = (const float*)d_in[2];
    const float* w1    = (const float*)d_in[3];
    const float* g1    = (const float*)d_in[4];
    const float* b1    = (const float*)d_in[5];
    const float* woff2 = (const float*)d_in[6];
    const float* wm2   = (const float*)d_in[7];
    const float* w2    = (const float*)d_in[8];
    const float* g2    = (const float*)d_in[9];
    const float* b2    = (const float*)d_in[10];
    const float* woff3 = (const float*)d_in[11];
    const float* wm3   = (const float*)d_in[12];
    const float* w3    = (const float*)d_in[13];
    const float* g3    = (const float*)d_in[14];
    const float* b3    = (const float*)d_in[15];
    const float* woff4 = (const float*)d_in[16];
    const float* wm4   = (const float*)d_in[17];
    const float* w4    = (const float*)d_in[18];
    const float* g4    = (const float*)d_in[19];
    const float* b4    = (const float*)d_in[20];
    const float* wpool = (const float*)d_in[21];
    const float* gp    = (const float*)d_in[22];
    const float* bp    = (const float*)d_in[23];
    const float* wfuse = (const float*)d_in[24];
    const float* gf    = (const float*)d_in[25];
    const float* bf    = (const float*)d_in[26];

    char* ws = (char*)d_ws;
    size_t off = 0;
    auto alloc = [&](size_t bytes) {
        off = (off + 255) & ~(size_t)255;
        size_t o = off; off += bytes; return o;
    };
    // zero-init region contiguous: offmod | ypre | outpre
    size_t off_offmod = alloc(128 * 2048 * 4);
    size_t off_ypre   = alloc((size_t)4 * 256 * 2048 * 4);
    size_t off_outpre = alloc(256 * 2048 * 4);
    // A1..A4 contiguous (Aall)
    size_t off_A1     = alloc((size_t)256 * 2048 * 2);
    size_t off_A2     = alloc((size_t)256 * 18432 * 2);
    size_t off_A3     = alloc((size_t)256 * 18432 * 2);
    size_t off_A4     = alloc((size_t)256 * 18432 * 2);
    size_t off_Aoff   = alloc((size_t)128 * 18432 * 2);
    size_t off_Afuse  = alloc((size_t)256 * 1280 * 2);
    size_t off_xcat   = alloc((size_t)2048 * 1280 * 2);
    size_t off_xT     = alloc((size_t)2 * 1024 * 2048 * 2);
    size_t off_dtab0  = alloc((size_t)9 * 2048 * 32);
    size_t off_dtab   = alloc((size_t)57344 * 32);
    size_t off_scsh   = alloc((size_t)4 * 512 * 4);
    size_t off_scshf  = alloc((size_t)512 * 4);
    size_t off_gap    = alloc((size_t)4096 * 4);
    size_t off_pfin   = alloc((size_t)512 * 4);
    (void)ws_size; (void)in_sizes; (void)n_in; (void)out_size;

    float* offmod = (float*)(ws + off_offmod);
    float* ypre   = (float*)(ws + off_ypre);
    float* outpre = (float*)(ws + off_outpre);
    short* Aall   = (short*)(ws + off_A1);
    short* A1     = (short*)(ws + off_A1);
    short* A2     = (short*)(ws + off_A2);
    short* A3     = (short*)(ws + off_A3);
    short* A4     = (short*)(ws + off_A4);
    short* Aoff   = (short*)(ws + off_Aoff);
    short* Afuse  = (short*)(ws + off_Afuse);
    short* xcat   = (short*)(ws + off_xcat);
    short* xT     = (short*)(ws + off_xT);
    int*   dtab0  = (int*)(ws + off_dtab0);
    int*   dtab   = (int*)(ws + off_dtab);
    float* scsh   = (float*)(ws + off_scsh);
    float* scshf  = (float*)(ws + off_scshf);
    float* gapb   = (float*)(ws + off_gap);
    float* pfin   = (float*)(ws + off_pfin);

    // 1. fused prep: zero | w1 | wfuse | dtab0 | convoff | convw9 | xpose | gap
    k_prep<<<10632, 256, 0, stream>>>(x, xT, w1, A1, wfuse, Afuse, dtab0,
                                      woff1, wm1, woff2, wm2, woff3, wm3, woff4, wm4, Aoff,
                                      w2, w3, w4, A2, A3, A4,
                                      (float4*)(ws + off_offmod), gapb);
    // 2. offset/mod conv GEMM (1-tap, 2-deep pipeline)
    k_ogemm<<<dim3(16, 1, 36), 256, 0, stream>>>(Aoff, dtab0, xT, offmod);
    // 3. sampling tables
    k_sample<<<224, 256, 0, stream>>>(offmod, dtab);
    // 4. merged 4-branch deform GEMM (256x128 tiles, 2-deep pipeline)
    k_dgemm<<<dim3(16, 1, 56), 512, 0, stream>>>(Aall, dtab, xT, ypre);
    // 5. branch BN stats + pool branch
    k_bnpool<<<dim3(256, 5), 256, 0, stream>>>(ypre, ypre + 524288, ypre + 2 * 524288, ypre + 3 * 524288,
                                               g1, g2, g3, g4, b1, b2, b3, b4, scsh,
                                               gapb, wpool, gp, bp, pfin);
    // 6. concat (BN+relu applied) as f16 [2048][1280], coalesced transpose
    k_xcat<<<dim3(32, 20), 256, 0, stream>>>(ypre, scsh, pfin, xcat);
    // 7. fuse GEMM
    k_fgemm<<<dim3(16, 2, 8), 256, 0, stream>>>(Afuse, xcat, outpre);
    // 8. final BN stats (grid y=1 -> bn path only)
    k_bnpool<<<dim3(256, 1), 256, 0, stream>>>(outpre, outpre, outpre, outpre,
                                               gf, gf, gf, gf, bf, bf, bf, bf, scshf,
                                               gapb, wpool, gp, bp, pfin);
    // 9. final BN apply + layout
    k_final<<<2048, 256, 0, stream>>>(outpre, scshf, (float*)d_out);
}

// Round 6
// 415.058 us; speedup vs baseline: 1.8063x; 1.8063x over previous
//
#include <hip/hip_runtime.h>
#include <hip/hip_fp16.h>
#include <cstdint>
#include <cstddef>

#define EPSV 1e-5f

typedef _Float16 f16x8 __attribute__((ext_vector_type(8)));
typedef float f32x4 __attribute__((ext_vector_type(4)));
typedef short short4v __attribute__((ext_vector_type(4)));

__device__ __forceinline__ short f2h(float f) {
    _Float16 h = (_Float16)f;
    union { _Float16 h; short s; } u; u.h = h; return u.s;
}
__device__ __forceinline__ __half2 u2h2(unsigned u) {
    union { unsigned u; __half2 h; } x; x.u = u; return x.h;
}
__device__ __forceinline__ unsigned packh2(float w) {
    _Float16 h = (_Float16)w;
    union { _Float16 h; unsigned short s; } u; u.h = h;
    return (unsigned)u.s * 0x10001u;
}

// ================= fused prep kernel =================
// ranges: [0,1024) zero | [1024,1536) w1 | [1536,1856) wfuse | [1856,1928) dtab0
//         [1928,2440) convoff | [2440,5512) convw9 | [5512,6536) xpose | [6536,10632) gap
__global__ __launch_bounds__(256) void k_prep(
    const float* __restrict__ x, short* __restrict__ xT,
    const float* __restrict__ w1, short* __restrict__ A1,
    const float* __restrict__ wfuse, short* __restrict__ Af,
    int* __restrict__ dtab0,
    const float* __restrict__ woff1, const float* __restrict__ wm1,
    const float* __restrict__ woff2, const float* __restrict__ wm2,
    const float* __restrict__ woff3, const float* __restrict__ wm3,
    const float* __restrict__ woff4, const float* __restrict__ wm4,
    short* __restrict__ Aoff,
    const float* __restrict__ w2, const float* __restrict__ w3, const float* __restrict__ w4,
    short* __restrict__ A2, short* __restrict__ A3, short* __restrict__ A4,
    float4* __restrict__ zbase, float* __restrict__ gap)
{
    __shared__ short lds9[4608];
    __shared__ float lsg[4];
    int bx = blockIdx.x, t = threadIdx.x;
    if (bx < 1024) {
        for (int i = bx * 256 + t; i < 720896; i += 262144)
            zbase[i] = float4{0.f, 0.f, 0.f, 0.f};
        return;
    }
    if (bx < 1536) {
        int i4 = (bx - 1024) * 256 + t;
        float4 v = ((const float4*)w1)[i4];
        ((short4v*)A1)[i4] = short4v{f2h(v.x), f2h(v.y), f2h(v.z), f2h(v.w)};
        return;
    }
    if (bx < 1856) {
        int i4 = (bx - 1536) * 256 + t;
        float4 v = ((const float4*)wfuse)[i4];
        ((short4v*)Af)[i4] = short4v{f2h(v.x), f2h(v.y), f2h(v.z), f2h(v.w)};
        return;
    }
    if (bx < 1928) {
        int i = (bx - 1856) * 256 + t;
        if (i >= 9 * 2048) return;
        int j = i >> 11, p = i & 2047;
        int hw = p & 1023, h = hw >> 5, w = hw & 31;
        int y = h + j / 3 - 1, xx = w + j % 3 - 1;
        bool v = (y >= 0 && y < 32 && xx >= 0 && xx < 32);
        int4 ii = {v ? y * 32 + xx : 0, 0, 0, 0};
        uint4 ww = {v ? packh2(1.f) : 0u, 0u, 0u, 0u};
        ((int4*)dtab0)[(size_t)i * 2] = ii;
        ((uint4*)dtab0)[(size_t)i * 2 + 1] = ww;
        return;
    }
    if (bx < 2440) {
        int qb = bx - 1928;
        int ch = qb >> 2, cch = qb & 3;
        short* dbase = Aoff + (size_t)ch * 18432 + cch * 512;
        if (ch >= 84) {
            #pragma unroll
            for (int s = 0; s < 18; s++) {
                int idx = s * 256 + t;
                int jj = idx >> 9, c = idx & 511;
                dbase[(size_t)jj * 2048 + c] = 0;
            }
            return;
        }
        const float* src; int oc;
        if (ch < 2)       { src = woff1; oc = ch; }
        else if (ch == 2) { src = wm1;   oc = 0; }
        else if (ch < 21) { src = woff2; oc = ch - 3; }
        else if (ch < 30) { src = wm2;   oc = ch - 21; }
        else if (ch < 48) { src = woff3; oc = ch - 30; }
        else if (ch < 57) { src = wm3;   oc = ch - 48; }
        else if (ch < 75) { src = woff4; oc = ch - 57; }
        else              { src = wm4;   oc = ch - 75; }
        const float* basep = src + ((size_t)oc * 2048 + cch * 512) * 9;
        #pragma unroll
        for (int s = 0; s < 18; s++) {
            int idx = s * 256 + t;
            int c = idx / 9, jj = idx - c * 9;
            lds9[jj * 512 + c] = f2h(basep[idx]);
        }
        __syncthreads();
        #pragma unroll
        for (int s = 0; s < 18; s++) {
            int idx = s * 256 + t;
            int jj = idx >> 9, c = idx & 511;
            dbase[(size_t)jj * 2048 + c] = lds9[idx];
        }
        return;
    }
    if (bx < 5512) {
        int qb = bx - 2440;
        int o = qb & 255, cch = (qb >> 8) & 3, br = qb >> 10;
        const float* src = br == 0 ? w2 : br == 1 ? w3 : w4;
        short* dst = br == 0 ? A2 : br == 1 ? A3 : A4;
        const float* basep = src + ((size_t)o * 2048 + cch * 512) * 9;
        #pragma unroll
        for (int s = 0; s < 18; s++) {
            int idx = s * 256 + t;
            int c = idx / 9, jj = idx - c * 9;
            lds9[jj * 512 + c] = f2h(basep[idx]);
        }
        __syncthreads();
        short* dbase = dst + (size_t)o * 18432 + cch * 512;
        #pragma unroll
        for (int s = 0; s < 18; s++) {
            int idx = s * 256 + t;
            int jj = idx >> 9, c = idx & 511;
            dbase[(size_t)jj * 2048 + c] = lds9[idx];
        }
        return;
    }
    if (bx < 6536) {
        int qb = bx - 5512;
        int hw0 = (qb & 15) * 64, c0 = ((qb >> 4) & 31) * 64, b = qb >> 9;
        const float* xb = x + (size_t)b * 2048 * 1024;
        int hwi = t & 63, cr = t >> 6;
        #pragma unroll
        for (int r = 0; r < 16; r++) {
            int cl = cr + r * 4;
            lds9[hwi * 72 + cl] = f2h(xb[(size_t)(c0 + cl) * 1024 + hw0 + hwi]);
        }
        __syncthreads();
        short* xTb = xT + (size_t)b * 1024 * 2048;
        int ci = t & 63, hr = t >> 6;
        #pragma unroll
        for (int r = 0; r < 16; r++) {
            int hwr = hr + r * 4;
            xTb[(size_t)(hw0 + hwr) * 2048 + c0 + ci] = lds9[hwr * 72 + ci];
        }
        return;
    }
    {
        int bc = bx - 6536;                 // [0,4096) = [b][c]
        const float* row = x + (size_t)bc * 1024;
        float s = row[t] + row[t + 256] + row[t + 512] + row[t + 768];
        #pragma unroll
        for (int off = 32; off; off >>= 1) s += __shfl_down(s, off);
        if ((t & 63) == 0) lsg[t >> 6] = s;
        __syncthreads();
        if (t == 0) gap[bc] = (lsg[0] + lsg[1] + lsg[2] + lsg[3]) * (1.f / 1024.f);
    }
}

// ---------------- deform sampling tables (ii + packed-f16 tap weights) ----------------
__global__ void k_sample(const float* OM, int* dtabi) {
    int i = blockIdx.x * 256 + threadIdx.x;
    if (i >= 57344) return;
    int br, j, p;
    if (i < 2048) { br = 0; j = 0; p = i; }
    else { int r = i - 2048; br = 1 + r / 18432; r %= 18432; j = r >> 11; p = r & 2047; }
    const int dil_[4] = {1, 6, 12, 18};
    const int pad_[4] = {0, 6, 12, 18};
    const int cho_[4] = {0, 3, 30, 57};
    const int chm_[4] = {2, 21, 48, 75};
    const int tbo_[4] = {0, 2048, 20480, 38912};
    int J = br ? 9 : 1;
    int dil = dil_[br], pad = pad_[br];
    int hw = p & 1023, h = hw >> 5, w = hw & 31;
    float offy = OM[(size_t)(cho_[br] + j) * 2048 + p];
    float offx = OM[(size_t)(cho_[br] + J + j) * 2048 + p];
    float mz   = OM[(size_t)(chm_[br] + j) * 2048 + p];
    float m = 1.f / (1.f + expf(-mz));
    int ky = j / 3, kx = j - ky * 3;
    float fh = (float)(h + ky * dil) + offy;
    float fw = (float)(w + kx * dil) + offx;
    int limi = 31 + 2 * pad;
    float lim = (float)limi;
    fh = fminf(fmaxf(fh, 0.f), lim);
    fw = fminf(fmaxf(fw, 0.f), lim);
    float y0f = floorf(fh), x0f = floorf(fw);
    float wy = fh - y0f, wx = fw - x0f;
    int y0 = (int)y0f, x0 = (int)x0f;
    int y1 = min(y0 + 1, limi), x1 = min(x0 + 1, limi);
    int4 ii; uint4 ww;
    {
        int yo = y0 - pad, xo = x0 - pad;
        bool v = ((unsigned)yo < 32u) && ((unsigned)xo < 32u);
        ii.x = v ? yo * 32 + xo : 0; ww.x = v ? packh2((1.f - wy) * (1.f - wx) * m) : 0u;
    }
    {
        int yo = y0 - pad, xo = x1 - pad;
        bool v = ((unsigned)yo < 32u) && ((unsigned)xo < 32u);
        ii.y = v ? yo * 32 + xo : 0; ww.y = v ? packh2((1.f - wy) * wx * m) : 0u;
    }
    {
        int yo = y1 - pad, xo = x0 - pad;
        bool v = ((unsigned)yo < 32u) && ((unsigned)xo < 32u);
        ii.z = v ? yo * 32 + xo : 0; ww.z = v ? packh2(wy * (1.f - wx) * m) : 0u;
    }
    {
        int yo = y1 - pad, xo = x1 - pad;
        bool v = ((unsigned)yo < 32u) && ((unsigned)xo < 32u);
        ii.w = v ? yo * 32 + xo : 0; ww.w = v ? packh2(wy * wx * m) : 0u;
    }
    int ent = tbo_[br] + j * 2048 + p;
    ((int4*)dtabi)[(size_t)ent * 2] = ii;
    ((uint4*)dtabi)[(size_t)ent * 2 + 1] = ww;
}

// ================= gather GEMM: 1-deep reg prefetch + LDS double-buffer =================
// (WM*64)x128 tile, BK=32, 16x16x32 f16. ONE barrier per K-step:
// write buf(s&1) -> barrier -> MFMA-read buf(s&1); next step writes the other buffer,
// so laggard readers are never overwritten (next same-buffer write is behind the next barrier).
template <int WM, int NTAP>
__device__ __forceinline__ void gemm_gather_f16(
    const short* __restrict__ A, const int* __restrict__ tab,
    const short* __restrict__ xT, float* __restrict__ C,
    int K, int kbeg, int kend, int nbase)
{
    constexpr int TPP = WM;          // threads per position
    constexpr int CPT = 32 / TPP;    // channels per thread
    constexpr int NG = CPT / 8;      // uint4 groups per tap
    __shared__ __align__(16) short At[2][WM * 64][40];
    __shared__ __align__(16) short Bt[2][128][40];
    int t = threadIdx.x;
    f32x4 acc[4][4] = {};

    int p = t / TPP;
    int q = (t % TPP) * CPT;
    int pg = nbase + p;
    int bb = nbase >> 10;
    int jj = kbeg >> 11;
    const int4* te = (const int4*)tab + ((size_t)jj * 2048 + pg) * 2;
    int4 ii = te[0];
    uint4 wp = *(const uint4*)(te + 1);
    __half2 wt0 = u2h2(wp.x), wt1 = u2h2(wp.y), wt2 = u2h2(wp.z), wt3 = u2h2(wp.w);
    const short* xbase = xT + (size_t)bb * 1024 * 2048 + q;
    const short* rp0 = xbase + (size_t)ii.x * 2048;
    const short* rp1 = xbase + (size_t)ii.y * 2048;
    const short* rp2 = xbase + (size_t)ii.z * 2048;
    const short* rp3 = xbase + (size_t)ii.w * 2048;

    int arow = t >> 1;
    int aseg = (t & 1) * 16;
    const short* Ar = A + (size_t)arow * K + aseg;

    int lane = t & 63, wv = t >> 6;
    int mq = (wv >> 1) * 64, nq = (wv & 1) * 64;
    int lm = lane & 15, quad = lane >> 4;

    uint4 Aa, Ab;
    uint4 G0[NG], G1[NG], G2[NG], G3[NG];

#define LDSTAGE(KK) { \
    int ck_ = (KK) & 2047; \
    Aa = *(const uint4*)(Ar + (KK)); \
    Ab = *(const uint4*)(Ar + (KK) + 8); \
    _Pragma("unroll") \
    for (int g = 0; g < NG; g++) { \
        int o8_ = ck_ + g * 8; \
        G0[g] = *(const uint4*)(rp0 + o8_); \
        if (NTAP == 4) { \
            G1[g] = *(const uint4*)(rp1 + o8_); \
            G2[g] = *(const uint4*)(rp2 + o8_); \
            G3[g] = *(const uint4*)(rp3 + o8_); \
        } \
    } }

    LDSTAGE(kbeg);
    int buf = 0;
    for (int k0 = kbeg; k0 < kend; k0 += 32) {
        // combine current gather in regs (VALU only)
        uint4 pk[NG];
        uint4 sAa = Aa, sAb = Ab;
        #pragma unroll
        for (int g = 0; g < NG; g++) {
            __half2 r0 = __hmul2(u2h2(G0[g].x), wt0);
            __half2 r1 = __hmul2(u2h2(G0[g].y), wt0);
            __half2 r2 = __hmul2(u2h2(G0[g].z), wt0);
            __half2 r3 = __hmul2(u2h2(G0[g].w), wt0);
            if (NTAP == 4) {
                r0 = __hfma2(u2h2(G1[g].x), wt1, r0);
                r1 = __hfma2(u2h2(G1[g].y), wt1, r1);
                r2 = __hfma2(u2h2(G1[g].z), wt1, r2);
                r3 = __hfma2(u2h2(G1[g].w), wt1, r3);
                r0 = __hfma2(u2h2(G2[g].x), wt2, r0);
                r1 = __hfma2(u2h2(G2[g].y), wt2, r1);
                r2 = __hfma2(u2h2(G2[g].z), wt2, r2);
                r3 = __hfma2(u2h2(G2[g].w), wt2, r3);
                r0 = __hfma2(u2h2(G3[g].x), wt3, r0);
                r1 = __hfma2(u2h2(G3[g].y), wt3, r1);
                r2 = __hfma2(u2h2(G3[g].z), wt3, r2);
                r3 = __hfma2(u2h2(G3[g].w), wt3, r3);
            }
            union { __half2 h[4]; uint4 u; } uu;
            uu.h[0] = r0; uu.h[1] = r1; uu.h[2] = r2; uu.h[3] = r3;
            pk[g] = uu.u;
        }
        // write current tile into buffer `buf` (other buffer may still be read by laggards)
        *(uint4*)&At[buf][arow][aseg]     = sAa;
        *(uint4*)&At[buf][arow][aseg + 8] = sAb;
        #pragma unroll
        for (int g = 0; g < NG; g++) *(uint4*)&Bt[buf][p][q + g * 8] = pk[g];
        // issue next-step loads (stay in flight across barrier + MFMA phase)
        {
            int kn = (k0 + 32 < kend) ? k0 + 32 : kbeg;
            LDSTAGE(kn);
        }
        __syncthreads();
        f16x8 af[4], bfv[4];
        #pragma unroll
        for (int f = 0; f < 4; f++) {
            af[f]  = *(const f16x8*)&At[buf][mq + f * 16 + lm][quad * 8];
            bfv[f] = *(const f16x8*)&Bt[buf][nq + f * 16 + lm][quad * 8];
        }
        #pragma unroll
        for (int fm = 0; fm < 4; fm++)
            #pragma unroll
            for (int fn = 0; fn < 4; fn++)
                acc[fm][fn] = __builtin_amdgcn_mfma_f32_16x16x32_f16(af[fm], bfv[fn], acc[fm][fn], 0, 0, 0);
        buf ^= 1;
    }
#undef LDSTAGE

    #pragma unroll
    for (int fm = 0; fm < 4; fm++) {
        int row0 = mq + fm * 16 + quad * 4;
        #pragma unroll
        for (int fn = 0; fn < 4; fn++) {
            int col = nbase + nq + fn * 16 + lm;
            #pragma unroll
            for (int r = 0; r < 4; r++)
                atomicAdd(&C[(size_t)(row0 + r) * 2048 + col], acc[fm][fn][r]);
        }
    }
}

// offset/mod conv GEMM: M=128, K=18432, kchunk=512, grid (16,1,36), block 256, 1 tap
__global__ __launch_bounds__(256, 4) void k_ogemm(const short* __restrict__ Aoff,
                                                  const int* __restrict__ dtab0,
                                                  const short* __restrict__ xT,
                                                  float* __restrict__ offmod) {
    int kbeg = blockIdx.z * 512;
    gemm_gather_f16<2, 1>(Aoff, dtab0, xT, offmod, 18432, kbeg, kbeg + 512, blockIdx.x * 128);
}

// merged 4-branch deform GEMM: M=256, kchunk=1024, grid (16,1,56), block 512, 4 taps
__global__ __launch_bounds__(512, 4) void k_dgemm(const short* __restrict__ Aall,
                                                  const int* __restrict__ dtab,
                                                  const short* __restrict__ xT,
                                                  float* __restrict__ ypre) {
    int z = blockIdx.z;
    int br, kbeg;
    if (z < 2) { br = 0; kbeg = z * 1024; }
    else { int zz = z - 2; br = 1 + zz / 18; kbeg = (zz % 18) * 1024; }
    const size_t aoffs[4] = {0, 524288, 524288 + 4718592, 524288 + 2 * (size_t)4718592};
    const int tbo[4] = {0, 2048, 20480, 38912};
    int K = br ? 18432 : 2048;
    gemm_gather_f16<4, 4>(Aall + aoffs[br], dtab + (size_t)tbo[br] * 8, xT,
                          ypre + (size_t)br * 524288, K, kbeg, kbeg + 1024, blockIdx.x * 128);
}

// fuse GEMM: dense B [2048][1280] f16, M=256, K=1280, kchunk=160, grid (16,2,8)
__global__ __launch_bounds__(256) void k_fgemm(const short* __restrict__ A,
                                               const short* __restrict__ Bp,
                                               float* __restrict__ C) {
    __shared__ __align__(16) short At[128][40];
    __shared__ __align__(16) short Bt[128][40];
    int t = threadIdx.x;
    int nbase = blockIdx.x * 128, mbase = blockIdx.y * 128;
    int kbeg = blockIdx.z * 160, kend = kbeg + 160;
    const int K = 1280;
    f32x4 acc[4][4] = {};
    int lane = t & 63, wv = t >> 6;
    int mq = (wv >> 1) * 64, nq = (wv & 1) * 64;
    int lm = lane & 15, quad = lane >> 4;
    for (int k0 = kbeg; k0 < kend; k0 += 32) {
        int row = t >> 2, seg = t & 3;
        *(uint4*)&At[row][seg * 8] = *(const uint4*)(A + (size_t)(mbase + row) * K + k0 + seg * 8);
        *(uint4*)&At[row + 64][seg * 8] = *(const uint4*)(A + (size_t)(mbase + row + 64) * K + k0 + seg * 8);
        *(uint4*)&Bt[row][seg * 8] = *(const uint4*)(Bp + (size_t)(nbase + row) * K + k0 + seg * 8);
        *(uint4*)&Bt[row + 64][seg * 8] = *(const uint4*)(Bp + (size_t)(nbase + row + 64) * K + k0 + seg * 8);
        __syncthreads();
        f16x8 af[4], bfv[4];
        #pragma unroll
        for (int f = 0; f < 4; f++) {
            af[f]  = *(const f16x8*)&At[mq + f * 16 + lm][quad * 8];
            bfv[f] = *(const f16x8*)&Bt[nq + f * 16 + lm][quad * 8];
        }
        #pragma unroll
        for (int fm = 0; fm < 4; fm++)
            #pragma unroll
            for (int fn = 0; fn < 4; fn++)
                acc[fm][fn] = __builtin_amdgcn_mfma_f32_16x16x32_f16(af[fm], bfv[fn], acc[fm][fn], 0, 0, 0);
        __syncthreads();
    }
    #pragma unroll
    for (int fm = 0; fm < 4; fm++) {
        int row0 = mbase + mq + fm * 16 + quad * 4;
        #pragma unroll
        for (int fn = 0; fn < 4; fn++) {
            int col = nbase + nq + fn * 16 + lm;
            #pragma unroll
            for (int r = 0; r < 4; r++)
                atomicAdd(&C[(size_t)(row0 + r) * 2048 + col], acc[fm][fn][r]);
        }
    }
}

// ---------------- BN stats (y<4) + pool branch (y==4) ----------------
__global__ void k_bnpool(const float* Y0, const float* Y1, const float* Y2, const float* Y3,
                         const float* g0, const float* g1, const float* g2, const float* g3,
                         const float* b0, const float* b1, const float* b2, const float* b3,
                         float* S,
                         const float* gap, const float* wpool, const float* gp,
                         const float* bp, float* pfin) {
    int br = blockIdx.y;
    int o = blockIdx.x, t = threadIdx.x;
    __shared__ float l0[4], l1[4];
    if (br == 4) {
        float s0 = 0.f, s1 = 0.f;
        const float* wr = wpool + (size_t)o * 2048;
        for (int c = t; c < 2048; c += 256) {
            float wv = wr[c];
            s0 += wv * gap[c];
            s1 += wv * gap[2048 + c];
        }
        #pragma unroll
        for (int off = 32; off; off >>= 1) { s0 += __shfl_down(s0, off); s1 += __shfl_down(s1, off); }
        int wv_ = t >> 6;
        if ((t & 63) == 0) { l0[wv_] = s0; l1[wv_] = s1; }
        __syncthreads();
        if (t == 0) {
            float p0 = l0[0] + l0[1] + l0[2] + l0[3];
            float p1 = l1[0] + l1[1] + l1[2] + l1[3];
            float mu = 0.5f * (p0 + p1);
            float d0 = p0 - mu, d1 = p1 - mu;
            float var = 0.5f * (d0 * d0 + d1 * d1);
            float r = rsqrtf(var + EPSV);
            pfin[o]       = fmaxf(d0 * r * gp[o] + bp[o], 0.f);
            pfin[256 + o] = fmaxf(d1 * r * gp[o] + bp[o], 0.f);
        }
        return;
    }
    const float* Y = br == 0 ? Y0 : br == 1 ? Y1 : br == 2 ? Y2 : Y3;
    const float* g = br == 0 ? g0 : br == 1 ? g1 : br == 2 ? g2 : g3;
    const float* b = br == 0 ? b0 : br == 1 ? b1 : br == 2 ? b2 : b3;
    float* so = S + (size_t)br * 512;
    const float* row = Y + (size_t)o * 2048;
    float s = 0.f, ss = 0.f;
    for (int i = t; i < 2048; i += 256) { float v = row[i]; s += v; ss += v * v; }
    #pragma unroll
    for (int off = 32; off; off >>= 1) { s += __shfl_down(s, off); ss += __shfl_down(ss, off); }
    int wv = t >> 6;
    if ((t & 63) == 0) { l0[wv] = s; l1[wv] = ss; }
    __syncthreads();
    if (t == 0) {
        s = l0[0] + l0[1] + l0[2] + l0[3];
        ss = l1[0] + l1[1] + l1[2] + l1[3];
        float mu = s * (1.f / 2048.f);
        float var = ss * (1.f / 2048.f) - mu * mu;
        float sc = g[o] * rsqrtf(var + EPSV);
        so[o] = sc;
        so[256 + o] = b[o] - mu * sc;
    }
}

// ---------------- xcat transpose: ypre[1024ch][2048p] (BN+relu) + pfin -> xcat[p][1280] f16 ----------------
__global__ void k_xcat(const float* __restrict__ ypre, const float* __restrict__ S,
                       const float* __restrict__ pfin, short* __restrict__ xcat) {
    int p0 = blockIdx.x * 64, ct = blockIdx.y;
    int t = threadIdx.x;
    if (ct >= 16) {
        int c0 = 1024 + (ct - 16) * 64;
        int ci = t & 63, pr = t >> 6;
        #pragma unroll
        for (int r = 0; r < 16; r++) {
            int pw = p0 + pr + r * 4;
            int b = pw >> 10;
            xcat[(size_t)pw * 1280 + c0 + ci] = f2h(pfin[b * 256 + (c0 - 1024) + ci]);
        }
        return;
    }
    __shared__ short tile[64][72];
    int c0 = ct * 64;
    int pi = t & 63, cr = t >> 6;
    #pragma unroll
    for (int r = 0; r < 16; r++) {
        int cl = cr + r * 4;
        int cg = c0 + cl;
        int br = cg >> 8, cc = cg & 255;
        float sc = S[br * 512 + cc], sh = S[br * 512 + 256 + cc];
        float v = fmaxf(ypre[(size_t)cg * 2048 + p0 + pi] * sc + sh, 0.f);
        tile[pi][cl] = f2h(v);
    }
    __syncthreads();
    int ci = t & 63, pr = t >> 6;
    #pragma unroll
    for (int r = 0; r < 16; r++) {
        int pw = pr + r * 4;
        xcat[(size_t)(p0 + pw) * 1280 + c0 + ci] = tile[pw][ci];
    }
}

// ---------------- final BN + relu + layout to [B][O][HW] ----------------
__global__ void k_final(const float* outpre, const float* S, float* dout) {
    int i = blockIdx.x * 256 + threadIdx.x;    // 524288
    int hw = i & 1023, o = (i >> 10) & 255, b = i >> 18;
    float v = outpre[(size_t)o * 2048 + b * 1024 + hw] * S[o] + S[256 + o];
    dout[i] = fmaxf(v, 0.f);
}

extern "C" void kernel_launch(void* const* d_in, const int* in_sizes, int n_in,
                              void* d_out, int out_size, void* d_ws, size_t ws_size,
                              hipStream_t stream) {
    const float* x     = (const float*)d_in[0];
    const float* woff1 = (const float*)d_in[1];
    const float* wm1   = (const float*)d_in[2];
    const float* w1    = (const float*)d_in[3];
    const float* g1    = (const float*)d_in[4];
    const float* b1    = (const float*)d_in[5];
    const float* woff2 = (const float*)d_in[6];
    const float* wm2   = (const float*)d_in[7];
    const float* w2    = (const float*)d_in[8];
    const float* g2    = (const float*)d_in[9];
    const float* b2    = (const float*)d_in[10];
    const float* woff3 = (const float*)d_in[11];
    const float* wm3   = (const float*)d_in[12];
    const float* w3    = (const float*)d_in[13];
    const float* g3    = (const float*)d_in[14];
    const float* b3    = (const float*)d_in[15];
    const float* woff4 = (const float*)d_in[16];
    const float* wm4   = (const float*)d_in[17];
    const float* w4    = (const float*)d_in[18];
    const float* g4    = (const float*)d_in[19];
    const float* b4    = (const float*)d_in[20];
    const float* wpool = (const float*)d_in[21];
    const float* gp    = (const float*)d_in[22];
    const float* bp    = (const float*)d_in[23];
    const float* wfuse = (const float*)d_in[24];
    const float* gf    = (const float*)d_in[25];
    const float* bf    = (const float*)d_in[26];

    char* ws = (char*)d_ws;
    size_t off = 0;
    auto alloc = [&](size_t bytes) {
        off = (off + 255) & ~(size_t)255;
        size_t o = off; off += bytes; return o;
    };
    // zero-init region contiguous: offmod | ypre | outpre
    size_t off_offmod = alloc(128 * 2048 * 4);
    size_t off_ypre   = alloc((size_t)4 * 256 * 2048 * 4);
    size_t off_outpre = alloc(256 * 2048 * 4);
    // A1..A4 contiguous (Aall)
    size_t off_A1     = alloc((size_t)256 * 2048 * 2);
    size_t off_A2     = alloc((size_t)256 * 18432 * 2);
    size_t off_A3     = alloc((size_t)256 * 18432 * 2);
    size_t off_A4     = alloc((size_t)256 * 18432 * 2);
    size_t off_Aoff   = alloc((size_t)128 * 18432 * 2);
    size_t off_Afuse  = alloc((size_t)256 * 1280 * 2);
    size_t off_xcat   = alloc((size_t)2048 * 1280 * 2);
    size_t off_xT     = alloc((size_t)2 * 1024 * 2048 * 2);
    size_t off_dtab0  = alloc((size_t)9 * 2048 * 32);
    size_t off_dtab   = alloc((size_t)57344 * 32);
    size_t off_scsh   = alloc((size_t)4 * 512 * 4);
    size_t off_scshf  = alloc((size_t)512 * 4);
    size_t off_gap    = alloc((size_t)4096 * 4);
    size_t off_pfin   = alloc((size_t)512 * 4);
    (void)ws_size; (void)in_sizes; (void)n_in; (void)out_size;

    float* offmod = (float*)(ws + off_offmod);
    float* ypre   = (float*)(ws + off_ypre);
    float* outpre = (float*)(ws + off_outpre);
    short* Aall   = (short*)(ws + off_A1);
    short* A1     = (short*)(ws + off_A1);
    short* A2     = (short*)(ws + off_A2);
    short* A3     = (short*)(ws + off_A3);
    short* A4     = (short*)(ws + off_A4);
    short* Aoff   = (short*)(ws + off_Aoff);
    short* Afuse  = (short*)(ws + off_Afuse);
    short* xcat   = (short*)(ws + off_xcat);
    short* xT     = (short*)(ws + off_xT);
    int*   dtab0  = (int*)(ws + off_dtab0);
    int*   dtab   = (int*)(ws + off_dtab);
    float* scsh   = (float*)(ws + off_scsh);
    float* scshf  = (float*)(ws + off_scshf);
    float* gapb   = (float*)(ws + off_gap);
    float* pfin   = (float*)(ws + off_pfin);

    // 1. fused prep: zero | w1 | wfuse | dtab0 | convoff | convw9 | xpose | gap
    k_prep<<<10632, 256, 0, stream>>>(x, xT, w1, A1, wfuse, Afuse, dtab0,
                                      woff1, wm1, woff2, wm2, woff3, wm3, woff4, wm4, Aoff,
                                      w2, w3, w4, A2, A3, A4,
                                      (float4*)(ws + off_offmod), gapb);
    // 2. offset/mod conv GEMM (1-tap, LDS double-buffer)
    k_ogemm<<<dim3(16, 1, 36), 256, 0, stream>>>(Aoff, dtab0, xT, offmod);
    // 3. sampling tables
    k_sample<<<224, 256, 0, stream>>>(offmod, dtab);
    // 4. merged 4-branch deform GEMM (256x128 tiles, LDS double-buffer)
    k_dgemm<<<dim3(16, 1, 56), 512, 0, stream>>>(Aall, dtab, xT, ypre);
    // 5. branch BN stats + pool branch
    k_bnpool<<<dim3(256, 5), 256, 0, stream>>>(ypre, ypre + 524288, ypre + 2 * 524288, ypre + 3 * 524288,
                                               g1, g2, g3, g4, b1, b2, b3, b4, scsh,
                                               gapb, wpool, gp, bp, pfin);
    // 6. concat (BN+relu applied) as f16 [2048][1280], coalesced transpose
    k_xcat<<<dim3(32, 20), 256, 0, stream>>>(ypre, scsh, pfin, xcat);
    // 7. fuse GEMM
    k_fgemm<<<dim3(16, 2, 8), 256, 0, stream>>>(Afuse, xcat, outpre);
    // 8. final BN stats (grid y=1 -> bn path only)
    k_bnpool<<<dim3(256, 1), 256, 0, stream>>>(outpre, outpre, outpre, outpre,
                                               gf, gf, gf, gf, bf, bf, bf, bf, scshf,
                                               gapb, wpool, gp, bp, pfin);
    // 9. final BN apply + layout
    k_final<<<2048, 256, 0, stream>>>(outpre, scshf, (float*)d_out);
}

// Round 7
// 372.333 us; speedup vs baseline: 2.0136x; 1.1147x over previous
//
#include <hip/hip_runtime.h>
#include <hip/hip_fp16.h>
#include <cstdint>
#include <cstddef>

#define EPSV 1e-5f

typedef _Float16 f16x8 __attribute__((ext_vector_type(8)));
typedef float f32x4 __attribute__((ext_vector_type(4)));
typedef short short4v __attribute__((ext_vector_type(4)));

__device__ __forceinline__ short f2h(float f) {
    _Float16 h = (_Float16)f;
    union { _Float16 h; short s; } u; u.h = h; return u.s;
}
__device__ __forceinline__ __half2 u2h2(unsigned u) {
    union { unsigned u; __half2 h; } x; x.u = u; return x.h;
}
__device__ __forceinline__ unsigned packh2(float w) {
    _Float16 h = (_Float16)w;
    union { _Float16 h; unsigned short s; } u; u.h = h;
    return (unsigned)u.s * 0x10001u;
}

// barrier that drains LDS ops only — prefetched global loads stay in flight (vmcnt untouched)
#define BARRIER_LGKM() asm volatile("s_waitcnt lgkmcnt(0)\n\ts_barrier" ::: "memory")

// ================= fused prep kernel =================
// ranges: [0,1024) zero | [1024,1536) w1 | [1536,1856) wfuse | [1856,1928) dtab0
//         [1928,2440) convoff | [2440,5512) convw9 | [5512,6536) xpose | [6536,10632) gap
__global__ __launch_bounds__(256) void k_prep(
    const float* __restrict__ x, short* __restrict__ xT,
    const float* __restrict__ w1, short* __restrict__ A1,
    const float* __restrict__ wfuse, short* __restrict__ Af,
    int* __restrict__ dtab0,
    const float* __restrict__ woff1, const float* __restrict__ wm1,
    const float* __restrict__ woff2, const float* __restrict__ wm2,
    const float* __restrict__ woff3, const float* __restrict__ wm3,
    const float* __restrict__ woff4, const float* __restrict__ wm4,
    short* __restrict__ Aoff,
    const float* __restrict__ w2, const float* __restrict__ w3, const float* __restrict__ w4,
    short* __restrict__ A2, short* __restrict__ A3, short* __restrict__ A4,
    float4* __restrict__ zbase, float* __restrict__ gap)
{
    __shared__ short lds9[4608];
    __shared__ float lsg[4];
    int bx = blockIdx.x, t = threadIdx.x;
    if (bx < 1024) {
        for (int i = bx * 256 + t; i < 720896; i += 262144)
            zbase[i] = float4{0.f, 0.f, 0.f, 0.f};
        return;
    }
    if (bx < 1536) {
        int i4 = (bx - 1024) * 256 + t;
        float4 v = ((const float4*)w1)[i4];
        ((short4v*)A1)[i4] = short4v{f2h(v.x), f2h(v.y), f2h(v.z), f2h(v.w)};
        return;
    }
    if (bx < 1856) {
        int i4 = (bx - 1536) * 256 + t;
        float4 v = ((const float4*)wfuse)[i4];
        ((short4v*)Af)[i4] = short4v{f2h(v.x), f2h(v.y), f2h(v.z), f2h(v.w)};
        return;
    }
    if (bx < 1928) {
        int i = (bx - 1856) * 256 + t;
        if (i >= 9 * 2048) return;
        int j = i >> 11, p = i & 2047;
        int hw = p & 1023, h = hw >> 5, w = hw & 31;
        int y = h + j / 3 - 1, xx = w + j % 3 - 1;
        bool v = (y >= 0 && y < 32 && xx >= 0 && xx < 32);
        int4 ii = {v ? y * 32 + xx : 0, 0, 0, 0};
        uint4 ww = {v ? packh2(1.f) : 0u, 0u, 0u, 0u};
        ((int4*)dtab0)[(size_t)i * 2] = ii;
        ((uint4*)dtab0)[(size_t)i * 2 + 1] = ww;
        return;
    }
    if (bx < 2440) {
        int qb = bx - 1928;
        int ch = qb >> 2, cch = qb & 3;
        short* dbase = Aoff + (size_t)ch * 18432 + cch * 512;
        if (ch >= 84) {
            #pragma unroll
            for (int s = 0; s < 18; s++) {
                int idx = s * 256 + t;
                int jj = idx >> 9, c = idx & 511;
                dbase[(size_t)jj * 2048 + c] = 0;
            }
            return;
        }
        const float* src; int oc;
        if (ch < 2)       { src = woff1; oc = ch; }
        else if (ch == 2) { src = wm1;   oc = 0; }
        else if (ch < 21) { src = woff2; oc = ch - 3; }
        else if (ch < 30) { src = wm2;   oc = ch - 21; }
        else if (ch < 48) { src = woff3; oc = ch - 30; }
        else if (ch < 57) { src = wm3;   oc = ch - 48; }
        else if (ch < 75) { src = woff4; oc = ch - 57; }
        else              { src = wm4;   oc = ch - 75; }
        const float* basep = src + ((size_t)oc * 2048 + cch * 512) * 9;
        #pragma unroll
        for (int s = 0; s < 18; s++) {
            int idx = s * 256 + t;
            int c = idx / 9, jj = idx - c * 9;
            lds9[jj * 512 + c] = f2h(basep[idx]);
        }
        __syncthreads();
        #pragma unroll
        for (int s = 0; s < 18; s++) {
            int idx = s * 256 + t;
            int jj = idx >> 9, c = idx & 511;
            dbase[(size_t)jj * 2048 + c] = lds9[idx];
        }
        return;
    }
    if (bx < 5512) {
        int qb = bx - 2440;
        int o = qb & 255, cch = (qb >> 8) & 3, br = qb >> 10;
        const float* src = br == 0 ? w2 : br == 1 ? w3 : w4;
        short* dst = br == 0 ? A2 : br == 1 ? A3 : A4;
        const float* basep = src + ((size_t)o * 2048 + cch * 512) * 9;
        #pragma unroll
        for (int s = 0; s < 18; s++) {
            int idx = s * 256 + t;
            int c = idx / 9, jj = idx - c * 9;
            lds9[jj * 512 + c] = f2h(basep[idx]);
        }
        __syncthreads();
        short* dbase = dst + (size_t)o * 18432 + cch * 512;
        #pragma unroll
        for (int s = 0; s < 18; s++) {
            int idx = s * 256 + t;
            int jj = idx >> 9, c = idx & 511;
            dbase[(size_t)jj * 2048 + c] = lds9[idx];
        }
        return;
    }
    if (bx < 6536) {
        int qb = bx - 5512;
        int hw0 = (qb & 15) * 64, c0 = ((qb >> 4) & 31) * 64, b = qb >> 9;
        const float* xb = x + (size_t)b * 2048 * 1024;
        int hwi = t & 63, cr = t >> 6;
        #pragma unroll
        for (int r = 0; r < 16; r++) {
            int cl = cr + r * 4;
            lds9[hwi * 72 + cl] = f2h(xb[(size_t)(c0 + cl) * 1024 + hw0 + hwi]);
        }
        __syncthreads();
        short* xTb = xT + (size_t)b * 1024 * 2048;
        int ci = t & 63, hr = t >> 6;
        #pragma unroll
        for (int r = 0; r < 16; r++) {
            int hwr = hr + r * 4;
            xTb[(size_t)(hw0 + hwr) * 2048 + c0 + ci] = lds9[hwr * 72 + ci];
        }
        return;
    }
    {
        int bc = bx - 6536;                 // [0,4096) = [b][c]
        const float* row = x + (size_t)bc * 1024;
        float s = row[t] + row[t + 256] + row[t + 512] + row[t + 768];
        #pragma unroll
        for (int off = 32; off; off >>= 1) s += __shfl_down(s, off);
        if ((t & 63) == 0) lsg[t >> 6] = s;
        __syncthreads();
        if (t == 0) gap[bc] = (lsg[0] + lsg[1] + lsg[2] + lsg[3]) * (1.f / 1024.f);
    }
}

// ---------------- deform sampling tables (ii + packed-f16 tap weights) ----------------
__global__ void k_sample(const float* OM, int* dtabi) {
    int i = blockIdx.x * 256 + threadIdx.x;
    if (i >= 57344) return;
    int br, j, p;
    if (i < 2048) { br = 0; j = 0; p = i; }
    else { int r = i - 2048; br = 1 + r / 18432; r %= 18432; j = r >> 11; p = r & 2047; }
    const int dil_[4] = {1, 6, 12, 18};
    const int pad_[4] = {0, 6, 12, 18};
    const int cho_[4] = {0, 3, 30, 57};
    const int chm_[4] = {2, 21, 48, 75};
    const int tbo_[4] = {0, 2048, 20480, 38912};
    int J = br ? 9 : 1;
    int dil = dil_[br], pad = pad_[br];
    int hw = p & 1023, h = hw >> 5, w = hw & 31;
    float offy = OM[(size_t)(cho_[br] + j) * 2048 + p];
    float offx = OM[(size_t)(cho_[br] + J + j) * 2048 + p];
    float mz   = OM[(size_t)(chm_[br] + j) * 2048 + p];
    float m = 1.f / (1.f + expf(-mz));
    int ky = j / 3, kx = j - ky * 3;
    float fh = (float)(h + ky * dil) + offy;
    float fw = (float)(w + kx * dil) + offx;
    int limi = 31 + 2 * pad;
    float lim = (float)limi;
    fh = fminf(fmaxf(fh, 0.f), lim);
    fw = fminf(fmaxf(fw, 0.f), lim);
    float y0f = floorf(fh), x0f = floorf(fw);
    float wy = fh - y0f, wx = fw - x0f;
    int y0 = (int)y0f, x0 = (int)x0f;
    int y1 = min(y0 + 1, limi), x1 = min(x0 + 1, limi);
    int4 ii; uint4 ww;
    {
        int yo = y0 - pad, xo = x0 - pad;
        bool v = ((unsigned)yo < 32u) && ((unsigned)xo < 32u);
        ii.x = v ? yo * 32 + xo : 0; ww.x = v ? packh2((1.f - wy) * (1.f - wx) * m) : 0u;
    }
    {
        int yo = y0 - pad, xo = x1 - pad;
        bool v = ((unsigned)yo < 32u) && ((unsigned)xo < 32u);
        ii.y = v ? yo * 32 + xo : 0; ww.y = v ? packh2((1.f - wy) * wx * m) : 0u;
    }
    {
        int yo = y1 - pad, xo = x0 - pad;
        bool v = ((unsigned)yo < 32u) && ((unsigned)xo < 32u);
        ii.z = v ? yo * 32 + xo : 0; ww.z = v ? packh2(wy * (1.f - wx) * m) : 0u;
    }
    {
        int yo = y1 - pad, xo = x1 - pad;
        bool v = ((unsigned)yo < 32u) && ((unsigned)xo < 32u);
        ii.w = v ? yo * 32 + xo : 0; ww.w = v ? packh2(wy * wx * m) : 0u;
    }
    int ent = tbo_[br] + j * 2048 + p;
    ((int4*)dtabi)[(size_t)ent * 2] = ii;
    ((uint4*)dtabi)[(size_t)ent * 2 + 1] = ww;
}

// ================= gather GEMM: 1-deep reg prefetch + LDS dbuf + lgkm-only barrier =================
// (WM*64)x128 tile, BK=32, 16x16x32 f16. One raw barrier per K-step; prefetched global
// gathers are NOT drained at the barrier (vmcnt untouched) — they fly a full step.
template <int WM, int NTAP>
__device__ __forceinline__ void gemm_gather_f16(
    const short* __restrict__ A, const int* __restrict__ tab,
    const short* __restrict__ xT, float* __restrict__ C,
    int K, int kbeg, int kend, int nbase)
{
    constexpr int TPP = WM;          // threads per position
    constexpr int CPT = 32 / TPP;    // channels per thread
    constexpr int NG = CPT / 8;      // uint4 groups per tap
    __shared__ __align__(16) short At[2][WM * 64][40];
    __shared__ __align__(16) short Bt[2][128][40];
    int t = threadIdx.x;
    f32x4 acc[4][4] = {};

    int p = t / TPP;
    int q = (t % TPP) * CPT;
    int pg = nbase + p;
    int bb = nbase >> 10;
    int jj = kbeg >> 11;
    const int4* te = (const int4*)tab + ((size_t)jj * 2048 + pg) * 2;
    int4 ii = te[0];
    uint4 wp = *(const uint4*)(te + 1);
    __half2 wt0 = u2h2(wp.x), wt1 = u2h2(wp.y), wt2 = u2h2(wp.z), wt3 = u2h2(wp.w);
    const short* xbase = xT + (size_t)bb * 1024 * 2048 + q;
    const short* rp0 = xbase + (size_t)ii.x * 2048;
    const short* rp1 = xbase + (size_t)ii.y * 2048;
    const short* rp2 = xbase + (size_t)ii.z * 2048;
    const short* rp3 = xbase + (size_t)ii.w * 2048;

    int arow = t >> 1;
    int aseg = (t & 1) * 16;
    const short* Ar = A + (size_t)arow * K + aseg;

    int lane = t & 63, wv = t >> 6;
    int mq = (wv >> 1) * 64, nq = (wv & 1) * 64;
    int lm = lane & 15, quad = lane >> 4;

    uint4 Aa, Ab;
    uint4 G0[NG], G1[NG], G2[NG], G3[NG];

#define LDSTAGE(KK) { \
    int ck_ = (KK) & 2047; \
    Aa = *(const uint4*)(Ar + (KK)); \
    Ab = *(const uint4*)(Ar + (KK) + 8); \
    _Pragma("unroll") \
    for (int g = 0; g < NG; g++) { \
        int o8_ = ck_ + g * 8; \
        G0[g] = *(const uint4*)(rp0 + o8_); \
        if (NTAP == 4) { \
            G1[g] = *(const uint4*)(rp1 + o8_); \
            G2[g] = *(const uint4*)(rp2 + o8_); \
            G3[g] = *(const uint4*)(rp3 + o8_); \
        } \
    } }

    LDSTAGE(kbeg);
    int buf = 0;
    for (int k0 = kbeg; k0 < kend; k0 += 32) {
        // combine current gather in regs (compiler inserts precise vmcnt waits here)
        uint4 pk[NG];
        uint4 sAa = Aa, sAb = Ab;
        #pragma unroll
        for (int g = 0; g < NG; g++) {
            __half2 r0 = __hmul2(u2h2(G0[g].x), wt0);
            __half2 r1 = __hmul2(u2h2(G0[g].y), wt0);
            __half2 r2 = __hmul2(u2h2(G0[g].z), wt0);
            __half2 r3 = __hmul2(u2h2(G0[g].w), wt0);
            if (NTAP == 4) {
                r0 = __hfma2(u2h2(G1[g].x), wt1, r0);
                r1 = __hfma2(u2h2(G1[g].y), wt1, r1);
                r2 = __hfma2(u2h2(G1[g].z), wt1, r2);
                r3 = __hfma2(u2h2(G1[g].w), wt1, r3);
                r0 = __hfma2(u2h2(G2[g].x), wt2, r0);
                r1 = __hfma2(u2h2(G2[g].y), wt2, r1);
                r2 = __hfma2(u2h2(G2[g].z), wt2, r2);
                r3 = __hfma2(u2h2(G2[g].w), wt2, r3);
                r0 = __hfma2(u2h2(G3[g].x), wt3, r0);
                r1 = __hfma2(u2h2(G3[g].y), wt3, r1);
                r2 = __hfma2(u2h2(G3[g].z), wt3, r2);
                r3 = __hfma2(u2h2(G3[g].w), wt3, r3);
            }
            union { __half2 h[4]; uint4 u; } uu;
            uu.h[0] = r0; uu.h[1] = r1; uu.h[2] = r2; uu.h[3] = r3;
            pk[g] = uu.u;
        }
        // issue next-step loads NOW — they stay in flight across barrier + MFMA phase
        {
            int kn = (k0 + 32 < kend) ? k0 + 32 : kbeg;
            LDSTAGE(kn);
        }
        // write current tile into buffer `buf`
        *(uint4*)&At[buf][arow][aseg]     = sAa;
        *(uint4*)&At[buf][arow][aseg + 8] = sAb;
        #pragma unroll
        for (int g = 0; g < NG; g++) *(uint4*)&Bt[buf][p][q + g * 8] = pk[g];
        BARRIER_LGKM();   // drains LDS writes only; global prefetch stays outstanding
        f16x8 af[4], bfv[4];
        #pragma unroll
        for (int f = 0; f < 4; f++) {
            af[f]  = *(const f16x8*)&At[buf][mq + f * 16 + lm][quad * 8];
            bfv[f] = *(const f16x8*)&Bt[buf][nq + f * 16 + lm][quad * 8];
        }
        #pragma unroll
        for (int fm = 0; fm < 4; fm++)
            #pragma unroll
            for (int fn = 0; fn < 4; fn++)
                acc[fm][fn] = __builtin_amdgcn_mfma_f32_16x16x32_f16(af[fm], bfv[fn], acc[fm][fn], 0, 0, 0);
        buf ^= 1;
    }
#undef LDSTAGE

    #pragma unroll
    for (int fm = 0; fm < 4; fm++) {
        int row0 = mq + fm * 16 + quad * 4;
        #pragma unroll
        for (int fn = 0; fn < 4; fn++) {
            int col = nbase + nq + fn * 16 + lm;
            #pragma unroll
            for (int r = 0; r < 4; r++)
                atomicAdd(&C[(size_t)(row0 + r) * 2048 + col], acc[fm][fn][r]);
        }
    }
}

// offset/mod conv GEMM: M=128, K=18432, kchunk=1024, grid (16,1,18), block 256, 1 tap
__global__ __launch_bounds__(256, 4) void k_ogemm(const short* __restrict__ Aoff,
                                                  const int* __restrict__ dtab0,
                                                  const short* __restrict__ xT,
                                                  float* __restrict__ offmod) {
    int kbeg = blockIdx.z * 1024;
    gemm_gather_f16<2, 1>(Aoff, dtab0, xT, offmod, 18432, kbeg, kbeg + 1024, blockIdx.x * 128);
}

// merged 4-branch deform GEMM: M=256, grid (16,1,29), block 512, 4 taps
// br0: kchunk 1024 (2 chunks); br1-3: kchunk 2048 (9 chunks each)
__global__ __launch_bounds__(512, 4) void k_dgemm(const short* __restrict__ Aall,
                                                  const int* __restrict__ dtab,
                                                  const short* __restrict__ xT,
                                                  float* __restrict__ ypre) {
    int z = blockIdx.z;
    int br, kbeg, kchunk;
    if (z < 2) { br = 0; kbeg = z * 1024; kchunk = 1024; }
    else { int zz = z - 2; br = 1 + zz / 9; kbeg = (zz % 9) * 2048; kchunk = 2048; }
    const size_t aoffs[4] = {0, 524288, 524288 + 4718592, 524288 + 2 * (size_t)4718592};
    const int tbo[4] = {0, 2048, 20480, 38912};
    int K = br ? 18432 : 2048;
    gemm_gather_f16<4, 4>(Aall + aoffs[br], dtab + (size_t)tbo[br] * 8, xT,
                          ypre + (size_t)br * 524288, K, kbeg, kbeg + kchunk, blockIdx.x * 128);
}

// fuse GEMM: dense B [2048][1280] f16, M=256, K=1280, kchunk=160, grid (16,2,8)
__global__ __launch_bounds__(256) void k_fgemm(const short* __restrict__ A,
                                               const short* __restrict__ Bp,
                                               float* __restrict__ C) {
    __shared__ __align__(16) short At[128][40];
    __shared__ __align__(16) short Bt[128][40];
    int t = threadIdx.x;
    int nbase = blockIdx.x * 128, mbase = blockIdx.y * 128;
    int kbeg = blockIdx.z * 160, kend = kbeg + 160;
    const int K = 1280;
    f32x4 acc[4][4] = {};
    int lane = t & 63, wv = t >> 6;
    int mq = (wv >> 1) * 64, nq = (wv & 1) * 64;
    int lm = lane & 15, quad = lane >> 4;
    for (int k0 = kbeg; k0 < kend; k0 += 32) {
        int row = t >> 2, seg = t & 3;
        *(uint4*)&At[row][seg * 8] = *(const uint4*)(A + (size_t)(mbase + row) * K + k0 + seg * 8);
        *(uint4*)&At[row + 64][seg * 8] = *(const uint4*)(A + (size_t)(mbase + row + 64) * K + k0 + seg * 8);
        *(uint4*)&Bt[row][seg * 8] = *(const uint4*)(Bp + (size_t)(nbase + row) * K + k0 + seg * 8);
        *(uint4*)&Bt[row + 64][seg * 8] = *(const uint4*)(Bp + (size_t)(nbase + row + 64) * K + k0 + seg * 8);
        __syncthreads();
        f16x8 af[4], bfv[4];
        #pragma unroll
        for (int f = 0; f < 4; f++) {
            af[f]  = *(const f16x8*)&At[mq + f * 16 + lm][quad * 8];
            bfv[f] = *(const f16x8*)&Bt[nq + f * 16 + lm][quad * 8];
        }
        #pragma unroll
        for (int fm = 0; fm < 4; fm++)
            #pragma unroll
            for (int fn = 0; fn < 4; fn++)
                acc[fm][fn] = __builtin_amdgcn_mfma_f32_16x16x32_f16(af[fm], bfv[fn], acc[fm][fn], 0, 0, 0);
        __syncthreads();
    }
    #pragma unroll
    for (int fm = 0; fm < 4; fm++) {
        int row0 = mbase + mq + fm * 16 + quad * 4;
        #pragma unroll
        for (int fn = 0; fn < 4; fn++) {
            int col = nbase + nq + fn * 16 + lm;
            #pragma unroll
            for (int r = 0; r < 4; r++)
                atomicAdd(&C[(size_t)(row0 + r) * 2048 + col], acc[fm][fn][r]);
        }
    }
}

// ---------------- BN stats (y<4) + pool branch (y==4) ----------------
__global__ void k_bnpool(const float* Y0, const float* Y1, const float* Y2, const float* Y3,
                         const float* g0, const float* g1, const float* g2, const float* g3,
                         const float* b0, const float* b1, const float* b2, const float* b3,
                         float* S,
                         const float* gap, const float* wpool, const float* gp,
                         const float* bp, float* pfin) {
    int br = blockIdx.y;
    int o = blockIdx.x, t = threadIdx.x;
    __shared__ float l0[4], l1[4];
    if (br == 4) {
        float s0 = 0.f, s1 = 0.f;
        const float* wr = wpool + (size_t)o * 2048;
        for (int c = t; c < 2048; c += 256) {
            float wv = wr[c];
            s0 += wv * gap[c];
            s1 += wv * gap[2048 + c];
        }
        #pragma unroll
        for (int off = 32; off; off >>= 1) { s0 += __shfl_down(s0, off); s1 += __shfl_down(s1, off); }
        int wv_ = t >> 6;
        if ((t & 63) == 0) { l0[wv_] = s0; l1[wv_] = s1; }
        __syncthreads();
        if (t == 0) {
            float p0 = l0[0] + l0[1] + l0[2] + l0[3];
            float p1 = l1[0] + l1[1] + l1[2] + l1[3];
            float mu = 0.5f * (p0 + p1);
            float d0 = p0 - mu, d1 = p1 - mu;
            float var = 0.5f * (d0 * d0 + d1 * d1);
            float r = rsqrtf(var + EPSV);
            pfin[o]       = fmaxf(d0 * r * gp[o] + bp[o], 0.f);
            pfin[256 + o] = fmaxf(d1 * r * gp[o] + bp[o], 0.f);
        }
        return;
    }
    const float* Y = br == 0 ? Y0 : br == 1 ? Y1 : br == 2 ? Y2 : Y3;
    const float* g = br == 0 ? g0 : br == 1 ? g1 : br == 2 ? g2 : g3;
    const float* b = br == 0 ? b0 : br == 1 ? b1 : br == 2 ? b2 : b3;
    float* so = S + (size_t)br * 512;
    const float* row = Y + (size_t)o * 2048;
    float s = 0.f, ss = 0.f;
    for (int i = t; i < 2048; i += 256) { float v = row[i]; s += v; ss += v * v; }
    #pragma unroll
    for (int off = 32; off; off >>= 1) { s += __shfl_down(s, off); ss += __shfl_down(ss, off); }
    int wv = t >> 6;
    if ((t & 63) == 0) { l0[wv] = s; l1[wv] = ss; }
    __syncthreads();
    if (t == 0) {
        s = l0[0] + l0[1] + l0[2] + l0[3];
        ss = l1[0] + l1[1] + l1[2] + l1[3];
        float mu = s * (1.f / 2048.f);
        float var = ss * (1.f / 2048.f) - mu * mu;
        float sc = g[o] * rsqrtf(var + EPSV);
        so[o] = sc;
        so[256 + o] = b[o] - mu * sc;
    }
}

// ---------------- xcat transpose: ypre[1024ch][2048p] (BN+relu) + pfin -> xcat[p][1280] f16 ----------------
__global__ void k_xcat(const float* __restrict__ ypre, const float* __restrict__ S,
                       const float* __restrict__ pfin, short* __restrict__ xcat) {
    int p0 = blockIdx.x * 64, ct = blockIdx.y;
    int t = threadIdx.x;
    if (ct >= 16) {
        int c0 = 1024 + (ct - 16) * 64;
        int ci = t & 63, pr = t >> 6;
        #pragma unroll
        for (int r = 0; r < 16; r++) {
            int pw = p0 + pr + r * 4;
            int b = pw >> 10;
            xcat[(size_t)pw * 1280 + c0 + ci] = f2h(pfin[b * 256 + (c0 - 1024) + ci]);
        }
        return;
    }
    __shared__ short tile[64][72];
    int c0 = ct * 64;
    int pi = t & 63, cr = t >> 6;
    #pragma unroll
    for (int r = 0; r < 16; r++) {
        int cl = cr + r * 4;
        int cg = c0 + cl;
        int br = cg >> 8, cc = cg & 255;
        float sc = S[br * 512 + cc], sh = S[br * 512 + 256 + cc];
        float v = fmaxf(ypre[(size_t)cg * 2048 + p0 + pi] * sc + sh, 0.f);
        tile[pi][cl] = f2h(v);
    }
    __syncthreads();
    int ci = t & 63, pr = t >> 6;
    #pragma unroll
    for (int r = 0; r < 16; r++) {
        int pw = pr + r * 4;
        xcat[(size_t)(p0 + pw) * 1280 + c0 + ci] = tile[pw][ci];
    }
}

// ---------------- final BN + relu + layout to [B][O][HW] ----------------
__global__ void k_final(const float* outpre, const float* S, float* dout) {
    int i = blockIdx.x * 256 + threadIdx.x;    // 524288
    int hw = i & 1023, o = (i >> 10) & 255, b = i >> 18;
    float v = outpre[(size_t)o * 2048 + b * 1024 + hw] * S[o] + S[256 + o];
    dout[i] = fmaxf(v, 0.f);
}

extern "C" void kernel_launch(void* const* d_in, const int* in_sizes, int n_in,
                              void* d_out, int out_size, void* d_ws, size_t ws_size,
                              hipStream_t stream) {
    const float* x     = (const float*)d_in[0];
    const float* woff1 = (const float*)d_in[1];
    const float* wm1   = (const float*)d_in[2];
    const float* w1    = (const float*)d_in[3];
    const float* g1    = (const float*)d_in[4];
    const float* b1    = (const float*)d_in[5];
    const float* woff2 = (const float*)d_in[6];
    const float* wm2   = (const float*)d_in[7];
    const float* w2    = (const float*)d_in[8];
    const float* g2    = (const float*)d_in[9];
    const float* b2    = (const float*)d_in[10];
    const float* woff3 = (const float*)d_in[11];
    const float* wm3   = (const float*)d_in[12];
    const float* w3    = (const float*)d_in[13];
    const float* g3    = (const float*)d_in[14];
    const float* b3    = (const float*)d_in[15];
    const float* woff4 = (const float*)d_in[16];
    const float* wm4   = (const float*)d_in[17];
    const float* w4    = (const float*)d_in[18];
    const float* g4    = (const float*)d_in[19];
    const float* b4    = (const float*)d_in[20];
    const float* wpool = (const float*)d_in[21];
    const float* gp    = (const float*)d_in[22];
    const float* bp    = (const float*)d_in[23];
    const float* wfuse = (const float*)d_in[24];
    const float* gf    = (const float*)d_in[25];
    const float* bf    = (const float*)d_in[26];

    char* ws = (char*)d_ws;
    size_t off = 0;
    auto alloc = [&](size_t bytes) {
        off = (off + 255) & ~(size_t)255;
        size_t o = off; off += bytes; return o;
    };
    // zero-init region contiguous: offmod | ypre | outpre
    size_t off_offmod = alloc(128 * 2048 * 4);
    size_t off_ypre   = alloc((size_t)4 * 256 * 2048 * 4);
    size_t off_outpre = alloc(256 * 2048 * 4);
    // A1..A4 contiguous (Aall)
    size_t off_A1     = alloc((size_t)256 * 2048 * 2);
    size_t off_A2     = alloc((size_t)256 * 18432 * 2);
    size_t off_A3     = alloc((size_t)256 * 18432 * 2);
    size_t off_A4     = alloc((size_t)256 * 18432 * 2);
    size_t off_Aoff   = alloc((size_t)128 * 18432 * 2);
    size_t off_Afuse  = alloc((size_t)256 * 1280 * 2);
    size_t off_xcat   = alloc((size_t)2048 * 1280 * 2);
    size_t off_xT     = alloc((size_t)2 * 1024 * 2048 * 2);
    size_t off_dtab0  = alloc((size_t)9 * 2048 * 32);
    size_t off_dtab   = alloc((size_t)57344 * 32);
    size_t off_scsh   = alloc((size_t)4 * 512 * 4);
    size_t off_scshf  = alloc((size_t)512 * 4);
    size_t off_gap    = alloc((size_t)4096 * 4);
    size_t off_pfin   = alloc((size_t)512 * 4);
    (void)ws_size; (void)in_sizes; (void)n_in; (void)out_size;

    float* offmod = (float*)(ws + off_offmod);
    float* ypre   = (float*)(ws + off_ypre);
    float* outpre = (float*)(ws + off_outpre);
    short* Aall   = (short*)(ws + off_A1);
    short* A1     = (short*)(ws + off_A1);
    short* A2     = (short*)(ws + off_A2);
    short* A3     = (short*)(ws + off_A3);
    short* A4     = (short*)(ws + off_A4);
    short* Aoff   = (short*)(ws + off_Aoff);
    short* Afuse  = (short*)(ws + off_Afuse);
    short* xcat   = (short*)(ws + off_xcat);
    short* xT     = (short*)(ws + off_xT);
    int*   dtab0  = (int*)(ws + off_dtab0);
    int*   dtab   = (int*)(ws + off_dtab);
    float* scsh   = (float*)(ws + off_scsh);
    float* scshf  = (float*)(ws + off_scshf);
    float* gapb   = (float*)(ws + off_gap);
    float* pfin   = (float*)(ws + off_pfin);

    // 1. fused prep: zero | w1 | wfuse | dtab0 | convoff | convw9 | xpose | gap
    k_prep<<<10632, 256, 0, stream>>>(x, xT, w1, A1, wfuse, Afuse, dtab0,
                                      woff1, wm1, woff2, wm2, woff3, wm3, woff4, wm4, Aoff,
                                      w2, w3, w4, A2, A3, A4,
                                      (float4*)(ws + off_offmod), gapb);
    // 2. offset/mod conv GEMM (1-tap, lgkm-barrier pipeline)
    k_ogemm<<<dim3(16, 1, 18), 256, 0, stream>>>(Aoff, dtab0, xT, offmod);
    // 3. sampling tables
    k_sample<<<224, 256, 0, stream>>>(offmod, dtab);
    // 4. merged 4-branch deform GEMM (256x128 tiles, lgkm-barrier pipeline)
    k_dgemm<<<dim3(16, 1, 29), 512, 0, stream>>>(Aall, dtab, xT, ypre);
    // 5. branch BN stats + pool branch
    k_bnpool<<<dim3(256, 5), 256, 0, stream>>>(ypre, ypre + 524288, ypre + 2 * 524288, ypre + 3 * 524288,
                                               g1, g2, g3, g4, b1, b2, b3, b4, scsh,
                                               gapb, wpool, gp, bp, pfin);
    // 6. concat (BN+relu applied) as f16 [2048][1280], coalesced transpose
    k_xcat<<<dim3(32, 20), 256, 0, stream>>>(ypre, scsh, pfin, xcat);
    // 7. fuse GEMM
    k_fgemm<<<dim3(16, 2, 8), 256, 0, stream>>>(Afuse, xcat, outpre);
    // 8. final BN stats (grid y=1 -> bn path only)
    k_bnpool<<<dim3(256, 1), 256, 0, stream>>>(outpre, outpre, outpre, outpre,
                                               gf, gf, gf, gf, bf, bf, bf, bf, scshf,
                                               gapb, wpool, gp, bp, pfin);
    // 9. final BN apply + layout
    k_final<<<2048, 256, 0, stream>>>(outpre, scshf, (float*)d_out);
}